// Round 1
// baseline (1494.912 us; speedup 1.0000x reference)
//
#include <hip/hip_runtime.h>
#include <math.h>

#define NN 100000
#define NE 1600000
#define NB 98        // ceil(NN/1024)
#define SSTR 292     // 288 padded to break 16-way LDS bank conflict

// ---------------- graph build ----------------
__global__ __launch_bounds__(256) void k_deg(const int* __restrict__ src,
                                             const int* __restrict__ dst,
                                             int* __restrict__ deg_out,
                                             int* __restrict__ deg_in) {
  int e = blockIdx.x * 256 + threadIdx.x;
  if (e < NE) {
    atomicAdd(&deg_out[src[e]], 1);
    atomicAdd(&deg_in[dst[e]], 1);
  }
}

__global__ __launch_bounds__(256) void k_bsum(const int* __restrict__ deg_in,
                                              int* __restrict__ bsum) {
  __shared__ int sd[256];
  int b = blockIdx.x, t = threadIdx.x;
  int base = b * 1024 + t * 4;
  int s = 0;
#pragma unroll
  for (int u = 0; u < 4; ++u) {
    int i = base + u;
    if (i < NN) s += deg_in[i];
  }
  sd[t] = s;
  __syncthreads();
  for (int st = 128; st > 0; st >>= 1) {
    if (t < st) sd[t] += sd[t + st];
    __syncthreads();
  }
  if (t == 0) bsum[b] = sd[0];
}

__global__ void k_bscan(const int* __restrict__ bsum, int* __restrict__ boff,
                        int* __restrict__ row_start) {
  if (threadIdx.x == 0 && blockIdx.x == 0) {
    int run = 0;
    for (int b = 0; b < NB; ++b) { boff[b] = run; run += bsum[b]; }
    row_start[NN] = run;  // == NE
  }
}

__global__ __launch_bounds__(256) void k_scan(const int* __restrict__ deg_in,
                                              const int* __restrict__ boff,
                                              int* __restrict__ row_start) {
  __shared__ int sd[256];
  int b = blockIdx.x, t = threadIdx.x;
  int base = b * 1024 + t * 4;
  int v0 = 0, v1 = 0, v2 = 0, v3 = 0;
  if (base + 0 < NN) v0 = deg_in[base + 0];
  if (base + 1 < NN) v1 = deg_in[base + 1];
  if (base + 2 < NN) v2 = deg_in[base + 2];
  if (base + 3 < NN) v3 = deg_in[base + 3];
  int s = v0 + v1 + v2 + v3;
  sd[t] = s;
  __syncthreads();
  for (int st = 1; st < 256; st <<= 1) {
    int add = (t >= st) ? sd[t - st] : 0;
    __syncthreads();
    sd[t] += add;
    __syncthreads();
  }
  int excl = (t ? sd[t - 1] : 0) + boff[b];
  if (base + 0 < NN) row_start[base + 0] = excl;
  excl += v0;
  if (base + 1 < NN) row_start[base + 1] = excl;
  excl += v1;
  if (base + 2 < NN) row_start[base + 2] = excl;
  excl += v2;
  if (base + 3 < NN) row_start[base + 3] = excl;
}

__global__ __launch_bounds__(256) void k_fill(const int* __restrict__ src,
                                              const int* __restrict__ dst,
                                              const float* __restrict__ ew,
                                              const int* __restrict__ deg_out,
                                              const int* __restrict__ row_start,
                                              int* __restrict__ cursor,
                                              int* __restrict__ csr_src,
                                              float* __restrict__ csr_w) {
  int e = blockIdx.x * 256 + threadIdx.x;
  if (e < NE) {
    int d = dst[e];
    int s = src[e];
    int p = row_start[d] + atomicAdd(&cursor[d], 1);
    csr_src[p] = s;
    csr_w[p] = ew[e] / fmaxf((float)deg_out[s], 1.0f);
  }
}

// ---------------- propagation (one wave per dst node) ----------------
__global__ __launch_bounds__(256) void k_prop_xh(const float* __restrict__ x,
                                                 const float* __restrict__ h,
                                                 float* __restrict__ out,
                                                 const int* __restrict__ row_start,
                                                 const int* __restrict__ csr_src,
                                                 const float* __restrict__ csr_w) {
  int wave = (blockIdx.x * 256 + threadIdx.x) >> 6;
  int lane = threadIdx.x & 63;
  if (wave >= NN) return;
  int beg = row_start[wave], end = row_start[wave + 1];
  float ah = 0.f, ax = 0.f;
  for (int p = beg; p < end; ++p) {
    int s = csr_src[p];
    float w = csr_w[p];
    ah = fmaf(w, h[(s << 6) + lane], ah);
    if (lane < 32) ax = fmaf(w, x[(s << 5) + lane], ax);
  }
  out[wave * 96 + 32 + lane] = ah;
  if (lane < 32) out[wave * 96 + lane] = ax;
}

__global__ __launch_bounds__(256) void k_prop96(const float* __restrict__ in,
                                                float* __restrict__ out,
                                                const int* __restrict__ row_start,
                                                const int* __restrict__ csr_src,
                                                const float* __restrict__ csr_w) {
  int wave = (blockIdx.x * 256 + threadIdx.x) >> 6;
  int lane = threadIdx.x & 63;
  if (wave >= NN) return;
  int beg = row_start[wave], end = row_start[wave + 1];
  float a = 0.f, b = 0.f;
  for (int p = beg; p < end; ++p) {
    int s = csr_src[p];
    float w = csr_w[p];
    a = fmaf(w, in[s * 96 + lane], a);
    if (lane < 32) b = fmaf(w, in[s * 96 + 64 + lane], b);
  }
  out[wave * 96 + lane] = a;
  if (lane < 32) out[wave * 96 + 64 + lane] = b;
}

__global__ __launch_bounds__(256) void k_prop64(const float* __restrict__ in,
                                                float* __restrict__ out,
                                                const int* __restrict__ row_start,
                                                const int* __restrict__ csr_src,
                                                const float* __restrict__ csr_w) {
  int wave = (blockIdx.x * 256 + threadIdx.x) >> 6;
  int lane = threadIdx.x & 63;
  if (wave >= NN) return;
  int beg = row_start[wave], end = row_start[wave + 1];
  float a = 0.f;
  for (int p = beg; p < end; ++p) {
    int s = csr_src[p];
    float w = csr_w[p];
    a = fmaf(w, in[(s << 6) + lane], a);
  }
  out[(wave << 6) + lane] = a;
}

// ---------------- gates ----------------
// 16 nodes/block, 16 threads/node, each thread does 4 output columns.
__global__ __launch_bounds__(256) void k_rz(const float* __restrict__ x,
                                            const float* __restrict__ h,
                                            const float* __restrict__ xh1,
                                            const float* __restrict__ xh2,
                                            const float* __restrict__ Wr,
                                            const float* __restrict__ br,
                                            const float* __restrict__ Wz,
                                            const float* __restrict__ bz,
                                            float* __restrict__ rh,
                                            float* __restrict__ zb) {
  __shared__ float sIn[16 * SSTR];
  int tid = threadIdx.x;
  int nb0 = blockIdx.x * 16;
  for (int idx = tid; idx < 16 * 288; idx += 256) {
    int ln = idx / 288, f = idx - ln * 288;
    int g = nb0 + ln;
    float v;
    if (f < 32) v = x[g * 32 + f];
    else if (f < 96) v = h[g * 64 + (f - 32)];
    else if (f < 192) v = xh1[g * 96 + (f - 96)];
    else v = xh2[g * 96 + (f - 192)];
    sIn[ln * SSTR + f] = v;
  }
  __syncthreads();
  int ln = tid >> 4, jg = tid & 15;
  const float* in = &sIn[ln * SSTR];
  int j0 = jg << 2;
  float ar0 = br[j0], ar1 = br[j0 + 1], ar2 = br[j0 + 2], ar3 = br[j0 + 3];
  float az0 = bz[j0], az1 = bz[j0 + 1], az2 = bz[j0 + 2], az3 = bz[j0 + 3];
  for (int t = 0; t < 3; ++t) {
    const float* wrB = Wr + t * 6144 + j0;
    const float* wzB = Wz + t * 6144 + j0;
    const float* aB = in + t * 96;
#pragma unroll 4
    for (int k = 0; k < 96; ++k) {
      float a = aB[k];
      float4 wr = *reinterpret_cast<const float4*>(wrB + (k << 6));
      float4 wz = *reinterpret_cast<const float4*>(wzB + (k << 6));
      ar0 = fmaf(a, wr.x, ar0); ar1 = fmaf(a, wr.y, ar1);
      ar2 = fmaf(a, wr.z, ar2); ar3 = fmaf(a, wr.w, ar3);
      az0 = fmaf(a, wz.x, az0); az1 = fmaf(a, wz.y, az1);
      az2 = fmaf(a, wz.z, az2); az3 = fmaf(a, wz.w, az3);
    }
  }
  int g = nb0 + ln;
  float4 h4 = *reinterpret_cast<const float4*>(h + (g << 6) + j0);
  float r0 = 1.f / (1.f + expf(-ar0)), r1 = 1.f / (1.f + expf(-ar1));
  float r2 = 1.f / (1.f + expf(-ar2)), r3 = 1.f / (1.f + expf(-ar3));
  float z0 = 1.f / (1.f + expf(-az0)), z1 = 1.f / (1.f + expf(-az1));
  float z2 = 1.f / (1.f + expf(-az2)), z3 = 1.f / (1.f + expf(-az3));
  *reinterpret_cast<float4*>(rh + (g << 6) + j0) =
      make_float4(r0 * h4.x, r1 * h4.y, r2 * h4.z, r3 * h4.w);
  *reinterpret_cast<float4*>(zb + (g << 6) + j0) = make_float4(z0, z1, z2, z3);
}

__global__ __launch_bounds__(256) void k_c(const float* __restrict__ x,
                                           const float* __restrict__ h,
                                           const float* __restrict__ rh,
                                           const float* __restrict__ xh1,
                                           const float* __restrict__ xh2,
                                           const float* __restrict__ rh1,
                                           const float* __restrict__ rh2,
                                           const float* __restrict__ Wc,
                                           const float* __restrict__ bc,
                                           const float* __restrict__ zb,
                                           float* __restrict__ out) {
  __shared__ float sIn[16 * SSTR];
  int tid = threadIdx.x;
  int nb0 = blockIdx.x * 16;
  for (int idx = tid; idx < 16 * 288; idx += 256) {
    int ln = idx / 288, f = idx - ln * 288;
    int g = nb0 + ln;
    float v;
    if (f < 32) v = x[g * 32 + f];
    else if (f < 96) v = rh[g * 64 + (f - 32)];
    else if (f < 128) v = xh1[g * 96 + (f - 96)];
    else if (f < 192) v = rh1[g * 64 + (f - 128)];
    else if (f < 224) v = xh2[g * 96 + (f - 192)];
    else v = rh2[g * 64 + (f - 224)];
    sIn[ln * SSTR + f] = v;
  }
  __syncthreads();
  int ln = tid >> 4, jg = tid & 15;
  const float* in = &sIn[ln * SSTR];
  int j0 = jg << 2;
  float a0 = bc[j0], a1 = bc[j0 + 1], a2 = bc[j0 + 2], a3 = bc[j0 + 3];
  for (int t = 0; t < 3; ++t) {
    const float* wB = Wc + t * 6144 + j0;
    const float* aB = in + t * 96;
#pragma unroll 4
    for (int k = 0; k < 96; ++k) {
      float a = aB[k];
      float4 w4 = *reinterpret_cast<const float4*>(wB + (k << 6));
      a0 = fmaf(a, w4.x, a0); a1 = fmaf(a, w4.y, a1);
      a2 = fmaf(a, w4.z, a2); a3 = fmaf(a, w4.w, a3);
    }
  }
  int g = nb0 + ln;
  float c0 = tanhf(a0), c1 = tanhf(a1), c2 = tanhf(a2), c3 = tanhf(a3);
  float4 h4 = *reinterpret_cast<const float4*>(h + (g << 6) + j0);
  float4 z4 = *reinterpret_cast<const float4*>(zb + (g << 6) + j0);
  float o0 = z4.x * h4.x + (1.f - z4.x) * c0;
  float o1 = z4.y * h4.y + (1.f - z4.y) * c1;
  float o2 = z4.z * h4.z + (1.f - z4.z) * c2;
  float o3 = z4.w * h4.w + (1.f - z4.w) * c3;
  *reinterpret_cast<float4*>(out + (g << 6) + j0) = make_float4(o0, o1, o2, o3);
}

// ---------------- launch ----------------
extern "C" void kernel_launch(void* const* d_in, const int* in_sizes, int n_in,
                              void* d_out, int out_size, void* d_ws, size_t ws_size,
                              hipStream_t stream) {
  const float* x = (const float*)d_in[0];
  const float* h = (const float*)d_in[1];
  const int* eidx = (const int*)d_in[2];
  const float* ew = (const float*)d_in[3];
  const float* Wr = (const float*)d_in[4];
  const float* br = (const float*)d_in[5];
  const float* Wz = (const float*)d_in[6];
  const float* bz = (const float*)d_in[7];
  const float* Wc = (const float*)d_in[8];
  const float* bc = (const float*)d_in[9];
  const int* src = eidx;
  const int* dst = eidx + NE;
  float* out = (float*)d_out;

  int* ip = (int*)d_ws;
  int* deg_out = ip;                 // NN
  int* deg_in = ip + NN;             // NN
  int* cursor = ip + 2 * NN;         // NN
  int* row_start = ip + 3 * NN;      // NN+1
  int* bsum = ip + 4 * NN + 64;      // NB (padded)
  int* boff = bsum + 128;            // NB
  int* csr_src = boff + 128;         // NE
  float* csr_w = (float*)(csr_src + NE);  // NE
  float* xh1 = csr_w + NE;           // NN*96
  float* xh2 = xh1 + NN * 96;        // NN*96
  float* rh = xh2 + NN * 96;         // NN*64
  float* rh1 = rh + NN * 64;         // NN*64
  float* rh2 = rh1 + NN * 64;        // NN*64
  float* zb = rh2 + NN * 64;         // NN*64

  hipMemsetAsync(ip, 0, (size_t)(3 * NN) * sizeof(int), stream);

  dim3 blk(256);
  k_deg<<<dim3(NE / 256), blk, 0, stream>>>(src, dst, deg_out, deg_in);
  k_bsum<<<dim3(NB), blk, 0, stream>>>(deg_in, bsum);
  k_bscan<<<dim3(1), dim3(64), 0, stream>>>(bsum, boff, row_start);
  k_scan<<<dim3(NB), blk, 0, stream>>>(deg_in, boff, row_start);
  k_fill<<<dim3(NE / 256), blk, 0, stream>>>(src, dst, ew, deg_out, row_start,
                                             cursor, csr_src, csr_w);

  k_prop_xh<<<dim3(NN / 4), blk, 0, stream>>>(x, h, xh1, row_start, csr_src, csr_w);
  k_prop96<<<dim3(NN / 4), blk, 0, stream>>>(xh1, xh2, row_start, csr_src, csr_w);
  k_rz<<<dim3(NN / 16), blk, 0, stream>>>(x, h, xh1, xh2, Wr, br, Wz, bz, rh, zb);
  k_prop64<<<dim3(NN / 4), blk, 0, stream>>>(rh, rh1, row_start, csr_src, csr_w);
  k_prop64<<<dim3(NN / 4), blk, 0, stream>>>(rh1, rh2, row_start, csr_src, csr_w);
  k_c<<<dim3(NN / 16), blk, 0, stream>>>(x, h, rh, xh1, xh2, rh1, rh2, Wc, bc, zb, out);
}

// Round 2
// 1202.414 us; speedup vs baseline: 1.2433x; 1.2433x over previous
//
#include <hip/hip_runtime.h>
#include <math.h>

#define NN 100000
#define NE 1600000
#define NB 98        // ceil(NN/1024)
#define GN 128       // nodes per gate-GEMM block
#define ASTR 132     // k-major act LDS stride (128+4): 16B-aligned, conflict-free

// ---------------- graph build ----------------
__global__ __launch_bounds__(256) void k_deg(const int* __restrict__ src,
                                             const int* __restrict__ dst,
                                             int* __restrict__ deg_out,
                                             int* __restrict__ deg_in) {
  int e = blockIdx.x * 256 + threadIdx.x;
  if (e < NE) {
    atomicAdd(&deg_out[src[e]], 1);
    atomicAdd(&deg_in[dst[e]], 1);
  }
}

__global__ __launch_bounds__(256) void k_bsum(const int* __restrict__ deg_in,
                                              int* __restrict__ bsum) {
  __shared__ int sd[256];
  int b = blockIdx.x, t = threadIdx.x;
  int base = b * 1024 + t * 4;
  int s = 0;
#pragma unroll
  for (int u = 0; u < 4; ++u) {
    int i = base + u;
    if (i < NN) s += deg_in[i];
  }
  sd[t] = s;
  __syncthreads();
  for (int st = 128; st > 0; st >>= 1) {
    if (t < st) sd[t] += sd[t + st];
    __syncthreads();
  }
  if (t == 0) bsum[b] = sd[0];
}

__global__ void k_bscan(const int* __restrict__ bsum, int* __restrict__ boff,
                        int* __restrict__ row_start) {
  if (threadIdx.x == 0 && blockIdx.x == 0) {
    int run = 0;
    for (int b = 0; b < NB; ++b) { boff[b] = run; run += bsum[b]; }
    row_start[NN] = run;  // == NE
  }
}

__global__ __launch_bounds__(256) void k_scan(const int* __restrict__ deg_in,
                                              const int* __restrict__ boff,
                                              int* __restrict__ row_start) {
  __shared__ int sd[256];
  int b = blockIdx.x, t = threadIdx.x;
  int base = b * 1024 + t * 4;
  int v0 = 0, v1 = 0, v2 = 0, v3 = 0;
  if (base + 0 < NN) v0 = deg_in[base + 0];
  if (base + 1 < NN) v1 = deg_in[base + 1];
  if (base + 2 < NN) v2 = deg_in[base + 2];
  if (base + 3 < NN) v3 = deg_in[base + 3];
  int s = v0 + v1 + v2 + v3;
  sd[t] = s;
  __syncthreads();
  for (int st = 1; st < 256; st <<= 1) {
    int add = (t >= st) ? sd[t - st] : 0;
    __syncthreads();
    sd[t] += add;
    __syncthreads();
  }
  int excl = (t ? sd[t - 1] : 0) + boff[b];
  if (base + 0 < NN) row_start[base + 0] = excl;
  excl += v0;
  if (base + 1 < NN) row_start[base + 1] = excl;
  excl += v1;
  if (base + 2 < NN) row_start[base + 2] = excl;
  excl += v2;
  if (base + 3 < NN) row_start[base + 3] = excl;
}

__global__ __launch_bounds__(256) void k_fill(const int* __restrict__ src,
                                              const int* __restrict__ dst,
                                              const float* __restrict__ ew,
                                              const int* __restrict__ deg_out,
                                              const int* __restrict__ row_start,
                                              int* __restrict__ cursor,
                                              int* __restrict__ csr_src,
                                              float* __restrict__ csr_w) {
  int e = blockIdx.x * 256 + threadIdx.x;
  if (e < NE) {
    int d = dst[e];
    int s = src[e];
    int p = row_start[d] + atomicAdd(&cursor[d], 1);
    csr_src[p] = s;
    csr_w[p] = ew[e] / fmaxf((float)deg_out[s], 1.0f);
  }
}

// ---------------- propagation (one wave per dst node) ----------------
__global__ __launch_bounds__(256) void k_prop_xh(const float* __restrict__ x,
                                                 const float* __restrict__ h,
                                                 float* __restrict__ out,
                                                 const int* __restrict__ row_start,
                                                 const int* __restrict__ csr_src,
                                                 const float* __restrict__ csr_w) {
  int wave = (blockIdx.x * 256 + threadIdx.x) >> 6;
  int lane = threadIdx.x & 63;
  if (wave >= NN) return;
  int beg = row_start[wave], end = row_start[wave + 1];
  float ah = 0.f, ax = 0.f;
  for (int p = beg; p < end; ++p) {
    int s = csr_src[p];
    float w = csr_w[p];
    ah = fmaf(w, h[(s << 6) + lane], ah);
    if (lane < 32) ax = fmaf(w, x[(s << 5) + lane], ax);
  }
  out[wave * 96 + 32 + lane] = ah;
  if (lane < 32) out[wave * 96 + lane] = ax;
}

__global__ __launch_bounds__(256) void k_prop96(const float* __restrict__ in,
                                                float* __restrict__ out,
                                                const int* __restrict__ row_start,
                                                const int* __restrict__ csr_src,
                                                const float* __restrict__ csr_w) {
  int wave = (blockIdx.x * 256 + threadIdx.x) >> 6;
  int lane = threadIdx.x & 63;
  if (wave >= NN) return;
  int beg = row_start[wave], end = row_start[wave + 1];
  float a = 0.f, b = 0.f;
  for (int p = beg; p < end; ++p) {
    int s = csr_src[p];
    float w = csr_w[p];
    a = fmaf(w, in[s * 96 + lane], a);
    if (lane < 32) b = fmaf(w, in[s * 96 + 64 + lane], b);
  }
  out[wave * 96 + lane] = a;
  if (lane < 32) out[wave * 96 + 64 + lane] = b;
}

__global__ __launch_bounds__(256) void k_prop64(const float* __restrict__ in,
                                                float* __restrict__ out,
                                                const int* __restrict__ row_start,
                                                const int* __restrict__ csr_src,
                                                const float* __restrict__ csr_w) {
  int wave = (blockIdx.x * 256 + threadIdx.x) >> 6;
  int lane = threadIdx.x & 63;
  if (wave >= NN) return;
  int beg = row_start[wave], end = row_start[wave + 1];
  float a = 0.f;
  for (int p = beg; p < end; ++p) {
    int s = csr_src[p];
    float w = csr_w[p];
    a = fmaf(w, in[(s << 6) + lane], a);
  }
  out[(wave << 6) + lane] = a;
}

// ---------------- gates: register-blocked GEMM ----------------
// 128 nodes/block, 256 threads. Thread = 4 cols (jg=tid&15) x 8 nodes (ng=tid>>4).
// Acts staged k-major in LDS (stride 132, conflict-free b128). W from global
// (one 256B row per k per wave; block-level reuse via L1/L2).

// stage one 96-wide tile for GN nodes into sA[k*ASTR + n], k-major.
// srcA: 32-wide array (or 96-wide when full96), srcB: 64-wide array.
__device__ __forceinline__ void stage_tile(float* sA, int nb0,
                                           const float* __restrict__ srcA, int ldA,
                                           const float* __restrict__ srcB, int ldB) {
  int tid = threadIdx.x;
  for (int idx = tid; idx < GN * 24; idx += 256) {
    int n = idx / 24, q = idx - n * 24;     // q = float4 index within 96
    int g = nb0 + n;
    float4 v = make_float4(0.f, 0.f, 0.f, 0.f);
    if (g < NN) {
      if (q < 8) v = *reinterpret_cast<const float4*>(srcA + (size_t)g * ldA + (q << 2));
      else       v = *reinterpret_cast<const float4*>(srcB + (size_t)g * ldB + ((q - 8) << 2));
    }
    int k = q << 2;
    sA[(k + 0) * ASTR + n] = v.x;
    sA[(k + 1) * ASTR + n] = v.y;
    sA[(k + 2) * ASTR + n] = v.z;
    sA[(k + 3) * ASTR + n] = v.w;
  }
}

__device__ __forceinline__ void stage_tile96(float* sA, int nb0,
                                             const float* __restrict__ src96) {
  int tid = threadIdx.x;
  for (int idx = tid; idx < GN * 24; idx += 256) {
    int n = idx / 24, q = idx - n * 24;
    int g = nb0 + n;
    float4 v = make_float4(0.f, 0.f, 0.f, 0.f);
    if (g < NN) v = *reinterpret_cast<const float4*>(src96 + (size_t)g * 96 + (q << 2));
    int k = q << 2;
    sA[(k + 0) * ASTR + n] = v.x;
    sA[(k + 1) * ASTR + n] = v.y;
    sA[(k + 2) * ASTR + n] = v.z;
    sA[(k + 3) * ASTR + n] = v.w;
  }
}

__global__ __launch_bounds__(256) void k_rz(const float* __restrict__ x,
                                            const float* __restrict__ h,
                                            const float* __restrict__ xh1,
                                            const float* __restrict__ xh2,
                                            const float* __restrict__ Wr,
                                            const float* __restrict__ br,
                                            const float* __restrict__ Wz,
                                            const float* __restrict__ bz,
                                            float* __restrict__ rh,
                                            float* __restrict__ zb) {
  __shared__ float sA[96 * ASTR];
  int tid = threadIdx.x;
  int nb0 = blockIdx.x * GN;
  int jg = tid & 15, ng = tid >> 4;
  int j0 = jg << 2, n0 = ng << 3;

  float4 b4r = *reinterpret_cast<const float4*>(br + j0);
  float4 b4z = *reinterpret_cast<const float4*>(bz + j0);
  float4 ar[8], az[8];
#pragma unroll
  for (int i = 0; i < 8; ++i) { ar[i] = b4r; az[i] = b4z; }

#pragma unroll
  for (int t = 0; t < 3; ++t) {
    if (t == 0) stage_tile(sA, nb0, x, 32, h, 64);
    else if (t == 1) stage_tile96(sA, nb0, xh1);
    else stage_tile96(sA, nb0, xh2);
    __syncthreads();
    const float* wrB = Wr + t * 6144 + j0;
    const float* wzB = Wz + t * 6144 + j0;
#pragma unroll 2
    for (int k = 0; k < 96; ++k) {
      float4 aa = *reinterpret_cast<const float4*>(&sA[k * ASTR + n0]);
      float4 ab = *reinterpret_cast<const float4*>(&sA[k * ASTR + n0 + 4]);
      float4 wr4 = *reinterpret_cast<const float4*>(wrB + (k << 6));
      float4 wz4 = *reinterpret_cast<const float4*>(wzB + (k << 6));
      float av[8] = {aa.x, aa.y, aa.z, aa.w, ab.x, ab.y, ab.z, ab.w};
#pragma unroll
      for (int i = 0; i < 8; ++i) {
        ar[i].x = fmaf(av[i], wr4.x, ar[i].x);
        ar[i].y = fmaf(av[i], wr4.y, ar[i].y);
        ar[i].z = fmaf(av[i], wr4.z, ar[i].z);
        ar[i].w = fmaf(av[i], wr4.w, ar[i].w);
        az[i].x = fmaf(av[i], wz4.x, az[i].x);
        az[i].y = fmaf(av[i], wz4.y, az[i].y);
        az[i].z = fmaf(av[i], wz4.z, az[i].z);
        az[i].w = fmaf(av[i], wz4.w, az[i].w);
      }
    }
    __syncthreads();
  }

#pragma unroll
  for (int i = 0; i < 8; ++i) {
    int g = nb0 + n0 + i;
    if (g < NN) {
      float4 h4 = *reinterpret_cast<const float4*>(h + (g << 6) + j0);
      float r0 = 1.f / (1.f + expf(-ar[i].x));
      float r1 = 1.f / (1.f + expf(-ar[i].y));
      float r2 = 1.f / (1.f + expf(-ar[i].z));
      float r3 = 1.f / (1.f + expf(-ar[i].w));
      float z0 = 1.f / (1.f + expf(-az[i].x));
      float z1 = 1.f / (1.f + expf(-az[i].y));
      float z2 = 1.f / (1.f + expf(-az[i].z));
      float z3 = 1.f / (1.f + expf(-az[i].w));
      *reinterpret_cast<float4*>(rh + (g << 6) + j0) =
          make_float4(r0 * h4.x, r1 * h4.y, r2 * h4.z, r3 * h4.w);
      *reinterpret_cast<float4*>(zb + (g << 6) + j0) = make_float4(z0, z1, z2, z3);
    }
  }
}

__global__ __launch_bounds__(256) void k_c(const float* __restrict__ x,
                                           const float* __restrict__ h,
                                           const float* __restrict__ rhf,
                                           const float* __restrict__ xh1,
                                           const float* __restrict__ xh2,
                                           const float* __restrict__ rh1,
                                           const float* __restrict__ rh2,
                                           const float* __restrict__ Wc,
                                           const float* __restrict__ bc,
                                           const float* __restrict__ zb,
                                           float* __restrict__ out) {
  __shared__ float sA[96 * ASTR];
  int tid = threadIdx.x;
  int nb0 = blockIdx.x * GN;
  int jg = tid & 15, ng = tid >> 4;
  int j0 = jg << 2, n0 = ng << 3;

  float4 b4c = *reinterpret_cast<const float4*>(bc + j0);
  float4 ac[8];
#pragma unroll
  for (int i = 0; i < 8; ++i) ac[i] = b4c;

#pragma unroll
  for (int t = 0; t < 3; ++t) {
    if (t == 0) stage_tile(sA, nb0, x, 32, rhf, 64);
    else if (t == 1) stage_tile(sA, nb0, xh1, 96, rh1, 64);
    else stage_tile(sA, nb0, xh2, 96, rh2, 64);
    __syncthreads();
    const float* wB = Wc + t * 6144 + j0;
#pragma unroll 2
    for (int k = 0; k < 96; ++k) {
      float4 aa = *reinterpret_cast<const float4*>(&sA[k * ASTR + n0]);
      float4 ab = *reinterpret_cast<const float4*>(&sA[k * ASTR + n0 + 4]);
      float4 w4 = *reinterpret_cast<const float4*>(wB + (k << 6));
      float av[8] = {aa.x, aa.y, aa.z, aa.w, ab.x, ab.y, ab.z, ab.w};
#pragma unroll
      for (int i = 0; i < 8; ++i) {
        ac[i].x = fmaf(av[i], w4.x, ac[i].x);
        ac[i].y = fmaf(av[i], w4.y, ac[i].y);
        ac[i].z = fmaf(av[i], w4.z, ac[i].z);
        ac[i].w = fmaf(av[i], w4.w, ac[i].w);
      }
    }
    __syncthreads();
  }

#pragma unroll
  for (int i = 0; i < 8; ++i) {
    int g = nb0 + n0 + i;
    if (g < NN) {
      float4 h4 = *reinterpret_cast<const float4*>(h + (g << 6) + j0);
      float4 z4 = *reinterpret_cast<const float4*>(zb + (g << 6) + j0);
      float c0 = tanhf(ac[i].x), c1 = tanhf(ac[i].y);
      float c2 = tanhf(ac[i].z), c3 = tanhf(ac[i].w);
      *reinterpret_cast<float4*>(out + (g << 6) + j0) = make_float4(
          z4.x * h4.x + (1.f - z4.x) * c0, z4.y * h4.y + (1.f - z4.y) * c1,
          z4.z * h4.z + (1.f - z4.z) * c2, z4.w * h4.w + (1.f - z4.w) * c3);
    }
  }
}

// ---------------- launch ----------------
extern "C" void kernel_launch(void* const* d_in, const int* in_sizes, int n_in,
                              void* d_out, int out_size, void* d_ws, size_t ws_size,
                              hipStream_t stream) {
  const float* x = (const float*)d_in[0];
  const float* h = (const float*)d_in[1];
  const int* eidx = (const int*)d_in[2];
  const float* ew = (const float*)d_in[3];
  const float* Wr = (const float*)d_in[4];
  const float* br = (const float*)d_in[5];
  const float* Wz = (const float*)d_in[6];
  const float* bz = (const float*)d_in[7];
  const float* Wc = (const float*)d_in[8];
  const float* bc = (const float*)d_in[9];
  const int* src = eidx;
  const int* dst = eidx + NE;
  float* out = (float*)d_out;

  int* ip = (int*)d_ws;
  int* deg_out = ip;                 // NN
  int* deg_in = ip + NN;             // NN
  int* cursor = ip + 2 * NN;         // NN
  int* row_start = ip + 3 * NN;      // NN+1
  int* bsum = ip + 4 * NN + 64;      // NB (padded)
  int* boff = bsum + 128;            // NB
  int* csr_src = boff + 128;         // NE
  float* csr_w = (float*)(csr_src + NE);  // NE
  float* xh1 = csr_w + NE;           // NN*96
  float* xh2 = xh1 + NN * 96;        // NN*96
  float* rh = xh2 + NN * 96;         // NN*64
  float* rh1 = rh + NN * 64;         // NN*64
  float* rh2 = rh1 + NN * 64;        // NN*64
  float* zb = rh2 + NN * 64;         // NN*64

  hipMemsetAsync(ip, 0, (size_t)(3 * NN) * sizeof(int), stream);

  dim3 blk(256);
  k_deg<<<dim3(NE / 256), blk, 0, stream>>>(src, dst, deg_out, deg_in);
  k_bsum<<<dim3(NB), blk, 0, stream>>>(deg_in, bsum);
  k_bscan<<<dim3(1), dim3(64), 0, stream>>>(bsum, boff, row_start);
  k_scan<<<dim3(NB), blk, 0, stream>>>(deg_in, boff, row_start);
  k_fill<<<dim3(NE / 256), blk, 0, stream>>>(src, dst, ew, deg_out, row_start,
                                             cursor, csr_src, csr_w);

  k_prop_xh<<<dim3(NN / 4), blk, 0, stream>>>(x, h, xh1, row_start, csr_src, csr_w);
  k_prop96<<<dim3(NN / 4), blk, 0, stream>>>(xh1, xh2, row_start, csr_src, csr_w);
  k_rz<<<dim3((NN + GN - 1) / GN), blk, 0, stream>>>(x, h, xh1, xh2, Wr, br, Wz, bz, rh, zb);
  k_prop64<<<dim3(NN / 4), blk, 0, stream>>>(rh, rh1, row_start, csr_src, csr_w);
  k_prop64<<<dim3(NN / 4), blk, 0, stream>>>(rh1, rh2, row_start, csr_src, csr_w);
  k_c<<<dim3((NN + GN - 1) / GN), blk, 0, stream>>>(x, h, rh, xh1, xh2, rh1, rh2, Wc, bc, zb, out);
}